// Round 12
// baseline (112.081 us; speedup 1.0000x reference)
//
#include <hip/hip_runtime.h>
#include <hip/hip_bf16.h>

// ---------------------------------------------------------------------------
// KroneNet fused kernel v19 for MI355X (gfx950)
// out[i][j] = softmax_j( s_a[i] * t_j[i] )
// History: v9/v13 ~36us best; v10 FAIL; v11 50 (spill at 128-cap); v12 45.5;
// v14 (L1->MFMA), v15 (no fences), v16 (256-band, old structure: compiler
// stayed at 64 regs -- structure didn't NEED more), v17 (64-band: 492MB
// spill), v18 (t-outer: lost MFMA ILP) -- all neutral. Plateau: no pipe
// >45% busy, pipes used serially, TLP fixed at 4 waves/SIMD.
// v19: MERGED-CHUNK + 256-REG BAND (the combination v16 was missing):
//   - process all 64 samples/wave at once (m=0..3 tiles): every W2 bfr
//     ds_read shared by 4 MFMAs -> LDS reads HALVED (the largest static
//     resource), 4 independent MFMA chains per t (ILP for 2-wave/SIMD)
//   - launch_bounds(512,2): need ~165 regs (af 4sx4m=64, partials 48,
//     xf 16, acc 16) -- fits 256 cap, 1 block/CU, 2 waves/SIMD
//   - w2b prefetched to 8 float4 regs before phase a (headroom exists now);
//     transition becomes regs->LDS, no exposed L2 latency at 1 block/CU
// All verified layouts kept (W2 pack map, W1F perm, red4 rotations, log2
// softmax, compact store). Tripwires: WRITE_SIZE >> 3MB = spill;
// dur >= 110 = TLP loss dominates -> close axis, revert to v13.
// ---------------------------------------------------------------------------

#define BTOT 262144
#define NBLK (BTOT / 512)   // 512 blocks x 512 samples (8 waves x 64)

typedef __attribute__((ext_vector_type(4))) float floatx4;
typedef __attribute__((ext_vector_type(8))) short bf16x8;
typedef __attribute__((ext_vector_type(4))) int  intx4;

// LDS layout (bytes), one W2 path resident at a time
#define OFF_W2    0          // 4 ksteps * 8 ntiles * 64 lanes * 16B = 32768
#define OFF_W1FA  32768      // 8 tiles * 64 lanes * 16B A-frags    = 8192
#define OFF_W1FB  40960      // 8192
#define OFF_B2A   49152      // 128 * float                         = 512
#define OFF_B2B   49664      // 512
#define OFF_W3A   50176      // 128 * float                         = 512
#define OFF_W3T   50688      // 128 * float4 (w3b transposed [n][j])= 2048
#define OFF_SA    52736      // 512 * float (s_a * log2e)           = 2048
#define LDS_TOTAL 54784

// pack two fp32 -> one dword of two bf16 (lo16=bf16(a), hi16=bf16(b)), RNE
static __device__ __forceinline__ int pack2bf(float lo, float hi) {
    int r;
    asm("v_cvt_pk_bf16_f32 %0, %1, %2" : "=v"(r) : "v"(lo), "v"(hi));
    return r;
}

// DPP-fused butterfly add. 0xB1=quad_perm xor1, 0x4E=quad_perm xor2,
// 0x124=row_ror:4, 0x128=row_ror:8
template <int CTRL>
static __device__ __forceinline__ float dppadd(float v) {
    int t = __builtin_amdgcn_update_dpp(0, __builtin_bit_cast(int, v),
                                        CTRL, 0xF, 0xF, true);
    return v + __builtin_bit_cast(float, t);
}

// Multiplexed 4-value reduce over 16 cols; lane c ends with the 16-col sum
// of a_{c&3}. Stages 3,4 are row_ror rotations (transversal preserves c&3;
// mirrors would mix samples -- the v10 bug).
static __device__ __forceinline__ float red4(float a0, float a1, float a2,
                                             float a3, int col) {
    float s0 = dppadd<0xB1>(a0), s1 = dppadd<0xB1>(a1);
    float s2 = dppadd<0xB1>(a2), s3 = dppadd<0xB1>(a3);
    float u0 = (col & 1) ? s1 : s0;
    float u1 = (col & 1) ? s3 : s2;
    float v0 = dppadd<0x4E>(u0), v1 = dppadd<0x4E>(u1);
    float w  = (col & 2) ? v1 : v0;
    w = dppadd<0x124>(w);
    w = dppadd<0x128>(w);
    return w;
}

// W2 LDS mapping (verified v5-v18): k=4*k4:
// dest = (s*8+t)*1024 + l*16 + (k&7)*2, s=k>>5, l=((k&31)>>3)*16+(n&15),
// t=n>>4. Lane remap keeps write conflicts <=4-way.
static __device__ __forceinline__ void w2_store(
        unsigned char* dst, int tid, int i, float4 f) {
    int n  = (tid & 15) | (i << 4);
    int k4 = tid >> 4;
    int k = k4 * 4;
    int s = k >> 5;
    int j0 = k & 7;               // 0 or 4
    int l = ((k & 31) >> 3) * 16 + (n & 15);
    int2 pkd;
    pkd.x = pack2bf(f.x, f.y);
    pkd.y = pack2bf(f.z, f.w);
    *(int2*)(dst + (s * 8 + (n >> 4)) * 1024 + l * 16 + j0 * 2) = pkd;
}

static __device__ __forceinline__ void pack_w2(
        unsigned char* dst, int tid, const float* __restrict__ w2) {
    const float4* w2p = (const float4*)w2;
    #pragma unroll
    for (int i = 0; i < 8; ++i) {
        int n  = (tid & 15) | (i << 4);
        int k4 = tid >> 4;
        w2_store(dst, tid, i, w2p[n * 32 + k4]);
    }
}

// Stage one path's W1+b1 as layer-1 MFMA A-fragments (verified v14-v18).
// Entry (tile tp, lane l): row perm n1 = (tp>>1)*32 + (l>>2)*8 + (tp&1)*4 +
// (l&3) so layer-1 D reg r == layer-2 A-frag j = (tp&1)*4+r.
static __device__ __forceinline__ void stage_w1f(
        unsigned char* smem, int off, int tid,
        const float* __restrict__ w1, const float* __restrict__ b1) {
    int tp = tid >> 6, l = tid & 63;
    intx4 e = (intx4){0, 0, 0, 0};
    if (l < 16) {
        int n1 = (tp >> 1) * 32 + (l >> 2) * 8 + (tp & 1) * 4 + (l & 3);
        float w0 = w1[2 * n1], w1v = w1[2 * n1 + 1], bb = b1[n1];
        int dhi = pack2bf(w0, w1v);
        float w0r = __builtin_bit_cast(float, dhi << 16);
        float w1r = __builtin_bit_cast(float, dhi & 0xffff0000);
        int dlo = pack2bf(w0 - w0r, w1v - w1r);
        int bh  = pack2bf(bb, 0.f);
        float bbr = __builtin_bit_cast(float, bh << 16);
        int dbias = pack2bf(bb, bb - bbr);
        e = (intx4){dhi, dlo, dhi, dbias};
    }
    ((intx4*)(smem + off))[tid] = e;
}

// Layer-1 B-fragment (hi/lo split): {pack(xhi), pack(xhi), pack(xlo), 1.0bf x2}
static __device__ __forceinline__ intx4 make_xfrag(float2 xx) {
    int d0 = pack2bf(xx.x, xx.y);
    float r0 = __builtin_bit_cast(float, d0 << 16);
    float r1 = __builtin_bit_cast(float, d0 & 0xffff0000);
    int d2 = pack2bf(xx.x - r0, xx.y - r1);
    return (intx4){d0, d0, d2, 0x3f803f80};
}

// Layer-1, all 4 m-tiles: af[s][m] ready as layer-2 A-frags.
// 8 ds_read_b128 (a0/a1 shared across m) + 32 MFMA + 64 pack.
#define LAYER1_ALL_M(af, XF, W1Fp)                                             \
    {                                                                          \
        const floatx4 zf = (floatx4){0.f, 0.f, 0.f, 0.f};                      \
        _Pragma("unroll")                                                      \
        for (int s = 0; s < 4; ++s) {                                          \
            bf16x8 a0 = (W1Fp)[(2 * s) * 64 + lane];                           \
            bf16x8 a1 = (W1Fp)[(2 * s + 1) * 64 + lane];                       \
            _Pragma("unroll")                                                  \
            for (int m = 0; m < 4; ++m) {                                      \
                floatx4 td0 = __builtin_amdgcn_mfma_f32_16x16x32_bf16(         \
                    a0, __builtin_bit_cast(bf16x8, (XF)[m]), zf, 0, 0, 0);     \
                floatx4 td1 = __builtin_amdgcn_mfma_f32_16x16x32_bf16(         \
                    a1, __builtin_bit_cast(bf16x8, (XF)[m]), zf, 0, 0, 0);     \
                af[s][m][0] = pack2bf(fmaxf(td0[0], 0.f), fmaxf(td0[1], 0.f)); \
                af[s][m][1] = pack2bf(fmaxf(td0[2], 0.f), fmaxf(td0[3], 0.f)); \
                af[s][m][2] = pack2bf(fmaxf(td1[0], 0.f), fmaxf(td1[1], 0.f)); \
                af[s][m][3] = pack2bf(fmaxf(td1[2], 0.f), fmaxf(td1[3], 0.f)); \
            }                                                                  \
        }                                                                      \
    }

// One t-tile, merged: 4 bfr reads, 16 MFMAs (4 independent m-chains).
#define TTILE_M(acc, af, W2p, b2n, t)                                          \
    floatx4 acc[4];                                                            \
    {                                                                          \
        _Pragma("unroll")                                                      \
        for (int m = 0; m < 4; ++m) acc[m] = (floatx4){b2n, b2n, b2n, b2n};    \
        _Pragma("unroll")                                                      \
        for (int s = 0; s < 4; ++s) {                                          \
            bf16x8 bfr = (W2p)[(s * 8 + (t)) * 64 + lane];                     \
            _Pragma("unroll")                                                  \
            for (int m = 0; m < 4; ++m)                                        \
                acc[m] = __builtin_amdgcn_mfma_f32_16x16x32_bf16(              \
                    __builtin_bit_cast(bf16x8, af[s][m]), bfr, acc[m],         \
                    0, 0, 0);                                                  \
        }                                                                      \
    }

// ---------------------------------------------------------------------------
// 512 blocks x 512 threads (8 waves). Per wave: 64 samples, merged (m=0..3).
//   xa loads + w2b reg-prefetch + weights + W2a pack -> sync ->
//   phase a (s_a -> LDS) -> xb loads -> sync -> W2b pack from regs -> sync
//   -> phase b (t_j, softmax, store)
// ---------------------------------------------------------------------------
__global__ __launch_bounds__(512, 2)
void krone_fused(const float* __restrict__ x,
                 const float* __restrict__ w1a, const float* __restrict__ w1b,
                 const float* __restrict__ b1a, const float* __restrict__ b1b,
                 const float* __restrict__ w2a, const float* __restrict__ w2b,
                 const float* __restrict__ b2a, const float* __restrict__ b2b,
                 const float* __restrict__ w3a, const float* __restrict__ w3b,
                 const float* __restrict__ b3a, const float* __restrict__ b3b,
                 float* __restrict__ out) {
    __shared__ __align__(16) unsigned char smem[LDS_TOTAL];

    const int tid  = threadIdx.x;
    const int lane = tid & 63;
    const int wave = tid >> 6;
    const int quad = lane >> 4;
    const int col  = lane & 15;
    const int wbase = blockIdx.x * 512 + wave * 64;

    const bf16x8* W2   = (const bf16x8*)(smem + OFF_W2);
    const bf16x8* W1FA = (const bf16x8*)(smem + OFF_W1FA);
    const bf16x8* W1FB = (const bf16x8*)(smem + OFF_W1FB);
    const float*  B2A  = (const float*)(smem + OFF_B2A);
    const float*  B2B  = (const float*)(smem + OFF_B2B);
    const float*  W3A  = (const float*)(smem + OFF_W3A);
    const floatx4* W3T = (const floatx4*)(smem + OFF_W3T);
    float*        SA   = (float*)(smem + OFF_SA);
    const float2* xA = (const float2*)x;
    const float2* xB = xA + BTOT;

    const float b3a_ = b3a[0];
    const float b30 = b3b[0], b31 = b3b[1], b32 = b3b[2];

    // ---- stage: x(a) loads + w2b reg-prefetch + weights + W2a pack ----
    float2 xv[4];   // [m], samples wbase + m*16 + col
    #pragma unroll
    for (int m = 0; m < 4; ++m) xv[m] = xA[wbase + m * 16 + col];

    float4 wb[8];   // w2b sources, held through phase a (32 regs)
    {
        const float4* w2bp = (const float4*)w2b;
        #pragma unroll
        for (int i = 0; i < 8; ++i) {
            int n  = (tid & 15) | (i << 4);
            int k4 = tid >> 4;
            wb[i] = w2bp[n * 32 + k4];
        }
    }

    pack_w2(smem + OFF_W2, tid, w2a);
    stage_w1f(smem, OFF_W1FA, tid, w1a, b1a);
    stage_w1f(smem, OFF_W1FB, tid, w1b, b1b);
    if (tid < 128) {
        ((float*)(smem + OFF_B2A))[tid] = b2a[tid];
        ((float*)(smem + OFF_B2B))[tid] = b2b[tid];
        ((float*)(smem + OFF_W3A))[tid] = w3a[tid];
    }
    if (tid < 384) {                                  // transpose w3b [3][128]
        int j = tid >> 7, n = tid & 127;              //  -> [128][4]
        ((float*)(smem + OFF_W3T))[n * 4 + j] = w3b[tid];
    }
    __syncthreads();

    // ---- phase a (64 samples merged) ----
    {
        intx4 xf[4];
        #pragma unroll
        for (int m = 0; m < 4; ++m) xf[m] = make_xfrag(xv[m]);
        intx4 af[4][4];
        LAYER1_ALL_M(af, xf, W1FA);

        float pa[4][4] = {};
        #pragma unroll
        for (int t = 0; t < 8; ++t) {
            float w3n = W3A[t * 16 + col];
            float b2n = B2A[t * 16 + col];
            TTILE_M(acc, af, W2, b2n, t);
            #pragma unroll
            for (int m = 0; m < 4; ++m)
                #pragma unroll
                for (int r = 0; r < 4; ++r)
                    pa[m][r] = fmaf(w3n, fmaxf(acc[m][r], 0.f), pa[m][r]);
        }
        #pragma unroll
        for (int m = 0; m < 4; ++m) {
            float w = red4(pa[m][0], pa[m][1], pa[m][2], pa[m][3], col);
            if (col < 4)
                SA[wave * 64 + m * 16 + quad * 4 + col] =
                    (w + b3a_) * 1.44269504089f;
        }
    }

    // ---- transition: xB loads, then W2b pack from registers ----
    #pragma unroll
    for (int m = 0; m < 4; ++m) xv[m] = xB[wbase + m * 16 + col];

    __syncthreads();   // everyone done reading W2a
    #pragma unroll
    for (int i = 0; i < 8; ++i)
        w2_store((unsigned char*)(smem + OFF_W2), tid, i, wb[i]);
    __syncthreads();

    // ---- phase b (merged) ----
    {
        intx4 xf[4];
        #pragma unroll
        for (int m = 0; m < 4; ++m) xf[m] = make_xfrag(xv[m]);
        intx4 af[4][4];
        LAYER1_ALL_M(af, xf, W1FB);

        float p0[4][4] = {}, p1[4][4] = {}, p2[4][4] = {};
        #pragma unroll
        for (int t = 0; t < 8; ++t) {
            floatx4 w3v = W3T[t * 16 + col];   // {w30,w31,w32,-}
            float b2n = B2B[t * 16 + col];
            TTILE_M(acc, af, W2, b2n, t);
            #pragma unroll
            for (int m = 0; m < 4; ++m)
                #pragma unroll
                for (int r = 0; r < 4; ++r) {
                    float h = fmaxf(acc[m][r], 0.f);
                    p0[m][r] = fmaf(w3v.x, h, p0[m][r]);
                    p1[m][r] = fmaf(w3v.y, h, p1[m][r]);
                    p2[m][r] = fmaf(w3v.z, h, p2[m][r]);
                }
        }
        #pragma unroll
        for (int m = 0; m < 4; ++m) {
            float t0 = red4(p0[m][0], p0[m][1], p0[m][2], p0[m][3], col) + b30;
            float t1 = red4(p1[m][0], p1[m][1], p1[m][2], p1[m][3], col) + b31;
            float t2 = red4(p2[m][0], p2[m][1], p2[m][2], p2[m][3], col) + b32;
            if (col < 4) {
                int sl = m * 16 + quad * 4 + col;
                float sa = SA[wave * 64 + sl];   // log2-scaled s_a
                float y0 = sa * t0, y1 = sa * t1, y2 = sa * t2;
                float mx = fmaxf(y0, fmaxf(y1, y2));
                float e0 = exp2f(y0 - mx), e1 = exp2f(y1 - mx),
                      e2 = exp2f(y2 - mx);
                float rs = __builtin_amdgcn_rcpf(e0 + e1 + e2);
                long o = (long)(wbase + sl) * 3;
                out[o]     = e0 * rs;
                out[o + 1] = e1 * rs;
                out[o + 2] = e2 * rs;
            }
        }
    }
}

extern "C" void kernel_launch(void* const* d_in, const int* in_sizes, int n_in,
                              void* d_out, int out_size, void* d_ws, size_t ws_size,
                              hipStream_t stream) {
    const float* x   = (const float*)d_in[0];
    const float* w1a = (const float*)d_in[1];
    const float* w1b = (const float*)d_in[2];
    const float* b1a = (const float*)d_in[3];
    const float* b1b = (const float*)d_in[4];
    const float* w2a = (const float*)d_in[5];
    const float* w2b = (const float*)d_in[6];
    const float* b2a = (const float*)d_in[7];
    const float* b2b = (const float*)d_in[8];
    const float* w3a = (const float*)d_in[9];
    const float* w3b = (const float*)d_in[10];
    const float* b3a = (const float*)d_in[11];
    const float* b3b = (const float*)d_in[12];
    float* out = (float*)d_out;

    krone_fused<<<NBLK, 512, 0, stream>>>(x, w1a, w1b, b1a, b1b, w2a, w2b,
                                          b2a, b2b, w3a, w3b, b3a, b3b, out);
}